// Round 6
// baseline (117.121 us; speedup 1.0000x reference)
//
#include <hip/hip_runtime.h>

// Problem constants (match reference)
#define NB 32
#define CH 3
#define HH 768
#define WW 768

// Tiling
#define TW 64
#define TH 32
#define SW 72                  // staged width: [tw0-4, tw0+68), 16B aligned
#define SH (TH + 4)            // 36 staged rows
#define CSTRIDE (SH * SW)      // LDS floats per channel plane
#define TPB 6                  // tiles per block (vertical chain)
#define NTC (WW / TW)          // 12
#define NTG (HH / (TH * TPB))  // 4
#define NWG (NB * NTC * NTG)   // 1536
#define UNITS (SH * (SW / 4))  // 648 float4-units per tile

__global__ __launch_bounds__(256, 2) void colwarp_conv_kernel(
    const float* __restrict__ im,
    const float* __restrict__ flat,
    float* __restrict__ out)
{
    // XCD-contiguous work mapping: XCD x gets works [x*NWG/8,(x+1)*NWG/8);
    // consecutive wids share (b,tc) and adjacent row-groups -> halo L2-local.
    const int d   = blockIdx.x;
    const int wid = (d & 7) * (NWG / 8) + (d >> 3);
    const int tg  = wid & 3;
    const int t2  = wid >> 2;
    const int tc  = t2 % NTC;
    const int b   = t2 / NTC;
    const int tw0 = tc * TW;
    const int thbase = tg * (TPB * TH);

    __shared__ float xs[2][CH][SH][SW];   // 62208 B -> 2 blocks/CU

    const int tid = threadIdx.x;

    // ---- per-sample params (b block-uniform -> scalar) ----
    const float* f = flat + b * 37;
    float Wm[3][3];
#pragma unroll
    for (int i = 0; i < 3; ++i)
#pragma unroll
        for (int j = 0; j < 3; ++j) Wm[i][j] = f[i * 3 + j];
    float sh3[3];
#pragma unroll
    for (int i = 0; i < 3; ++i) sh3[i] = f[9 + i];
    float K[5][5];
#pragma unroll
    for (int i = 0; i < 5; ++i)
#pragma unroll
        for (int j = 0; j < 5; ++j) K[i][j] = f[12 + i * 5 + j];
    float bias[3];
#pragma unroll
    for (int c = 0; c < 3; ++c)
        bias[c] = sh3[0]*Wm[0][c] + sh3[1]*Wm[1][c] + sh3[2]*Wm[2][c];

    const size_t plane = (size_t)HH * WW;
    const float* im0 = im + (size_t)b * CH * plane;

    // ---- this thread's staging units: u, u+256, u+512 ----
    int ur[3], uldso[3], ugw[3];
    bool uon[3];
#pragma unroll
    for (int ui = 0; ui < 3; ++ui) {
        const int u  = tid + 256 * ui;
        const int rr = u / (SW / 4);
        const int c4 = u - rr * (SW / 4);
        ur[ui]    = rr;
        uldso[ui] = rr * SW + c4 * 4;
        ugw[ui]   = tw0 - 4 + c4 * 4;
        uon[ui]   = (u < UNITS);
    }

    float4 v[3][CH];   // in-flight raw loads (issue-early, write-late)
    bool vok[3];

#define STAGE_LOAD(TH0)                                                        \
    _Pragma("unroll")                                                          \
    for (int ui = 0; ui < 3; ++ui) {                                           \
        const int gh = (TH0) + ur[ui] - 2;                                     \
        const bool ok = uon[ui] && ((unsigned)gh < (unsigned)HH)               \
                                && ((unsigned)ugw[ui] < (unsigned)WW);         \
        vok[ui] = ok;                                                          \
        if (ok) {                                                              \
            const size_t off = (size_t)gh * WW + ugw[ui];                      \
            v[ui][0] = *(const float4*)(im0 + off);                            \
            v[ui][1] = *(const float4*)(im0 + plane + off);                    \
            v[ui][2] = *(const float4*)(im0 + 2 * plane + off);                \
        }                                                                      \
    }

#define STAGE_WRITE(BASE)                                                      \
    _Pragma("unroll")                                                          \
    for (int ui = 0; ui < 3; ++ui) {                                           \
        if (uon[ui]) {                                                         \
            float4 m0 = make_float4(0.f, 0.f, 0.f, 0.f), m1 = m0, m2 = m0;     \
            if (vok[ui]) {                                                     \
                const float4 a0 = v[ui][0], a1 = v[ui][1], a2 = v[ui][2];      \
                m0.x = a0.x*Wm[0][0] + a1.x*Wm[1][0] + a2.x*Wm[2][0] + bias[0];\
                m0.y = a0.y*Wm[0][0] + a1.y*Wm[1][0] + a2.y*Wm[2][0] + bias[0];\
                m0.z = a0.z*Wm[0][0] + a1.z*Wm[1][0] + a2.z*Wm[2][0] + bias[0];\
                m0.w = a0.w*Wm[0][0] + a1.w*Wm[1][0] + a2.w*Wm[2][0] + bias[0];\
                m1.x = a0.x*Wm[0][1] + a1.x*Wm[1][1] + a2.x*Wm[2][1] + bias[1];\
                m1.y = a0.y*Wm[0][1] + a1.y*Wm[1][1] + a2.y*Wm[2][1] + bias[1];\
                m1.z = a0.z*Wm[0][1] + a1.z*Wm[1][1] + a2.z*Wm[2][1] + bias[1];\
                m1.w = a0.w*Wm[0][1] + a1.w*Wm[1][1] + a2.w*Wm[2][1] + bias[1];\
                m2.x = a0.x*Wm[0][2] + a1.x*Wm[1][2] + a2.x*Wm[2][2] + bias[2];\
                m2.y = a0.y*Wm[0][2] + a1.y*Wm[1][2] + a2.y*Wm[2][2] + bias[2];\
                m2.z = a0.z*Wm[0][2] + a1.z*Wm[1][2] + a2.z*Wm[2][2] + bias[2];\
                m2.w = a0.w*Wm[0][2] + a1.w*Wm[1][2] + a2.w*Wm[2][2] + bias[2];\
            }                                                                  \
            *(float4*)((BASE) + 0 * CSTRIDE + uldso[ui]) = m0;                 \
            *(float4*)((BASE) + 1 * CSTRIDE + uldso[ui]) = m1;                 \
            *(float4*)((BASE) + 2 * CSTRIDE + uldso[ui]) = m2;                 \
        }                                                                      \
    }

    const int tx = tid & 15;   // 4 output cols each
    const int ty = tid >> 4;   // 2 output rows each
    const int r0 = ty * 2;

#define CONV_STORE(XB, TH0)                                                    \
    {                                                                          \
        float acc[CH][2][4];                                                   \
        _Pragma("unroll")                                                      \
        for (int c = 0; c < CH; ++c)                                           \
            _Pragma("unroll")                                                  \
            for (int r = 0; r < 2; ++r)                                        \
                _Pragma("unroll")                                              \
                for (int o = 0; o < 4; ++o) acc[c][r][o] = 0.f;                \
        _Pragma("unroll")                                                      \
        for (int rr = 0; rr < 6; ++rr) {                                       \
            _Pragma("unroll")                                                  \
            for (int c = 0; c < CH; ++c) {                                     \
                const float2* rp = (const float2*)((XB) + c * CSTRIDE          \
                                       + (r0 + rr) * SW + 2 + tx * 4);         \
                const float2 p0 = rp[0], p1 = rp[1], p2 = rp[2], p3 = rp[3];   \
                const float w8[8] = {p0.x, p0.y, p1.x, p1.y,                   \
                                     p2.x, p2.y, p3.x, p3.y};                  \
                _Pragma("unroll")                                              \
                for (int i = 0; i < 5; ++i) {                                  \
                    const int r = rr - i;                                      \
                    if (r >= 0 && r < 2) {                                     \
                        _Pragma("unroll")                                      \
                        for (int j = 0; j < 5; ++j) {                          \
                            _Pragma("unroll")                                  \
                            for (int o = 0; o < 4; ++o)                        \
                                acc[c][r][o] += w8[o + j] * K[i][j];           \
                        }                                                      \
                    }                                                          \
                }                                                              \
            }                                                                  \
        }                                                                      \
        _Pragma("unroll")                                                      \
        for (int c = 0; c < CH; ++c) {                                         \
            float* ob = out + ((size_t)b * CH + c) * plane;                    \
            _Pragma("unroll")                                                  \
            for (int r = 0; r < 2; ++r) {                                      \
                const float4 vv = make_float4(acc[c][r][0], acc[c][r][1],      \
                                              acc[c][r][2], acc[c][r][3]);     \
                *(float4*)&ob[(size_t)((TH0) + r0 + r) * WW + tw0 + tx * 4] = vv; \
            }                                                                  \
        }                                                                      \
    }

    // ---- prologue: stage tile 0 ----
    STAGE_LOAD(thbase);
    STAGE_WRITE(&xs[0][0][0][0]);
    __syncthreads();

    // ---- pipelined chain: conv(cur) overlapped with stage(next) ----
#pragma unroll 1
    for (int t = 0; t < TPB; ++t) {
        float* xb  = &xs[t & 1][0][0][0];
        float* xnb = &xs[(t & 1) ^ 1][0][0][0];
        const int th0 = thbase + t * TH;
        if (t + 1 < TPB) { STAGE_LOAD(th0 + TH); }   // issue loads early
        CONV_STORE(xb, th0);                          // compute under the latency
        if (t + 1 < TPB) { STAGE_WRITE(xnb); }        // mix + LDS write late
        __syncthreads();
    }
}

extern "C" void kernel_launch(void* const* d_in, const int* in_sizes, int n_in,
                              void* d_out, int out_size, void* d_ws, size_t ws_size,
                              hipStream_t stream) {
    const float* im   = (const float*)d_in[0];
    const float* flat = (const float*)d_in[1];
    float* out        = (float*)d_out;

    colwarp_conv_kernel<<<dim3(NWG), dim3(256), 0, stream>>>(im, flat, out);
}

// Round 7
// 111.571 us; speedup vs baseline: 1.0497x; 1.0497x over previous
//
#include <hip/hip_runtime.h>

// Problem constants (match reference)
#define NB 32
#define CH 3
#define HH 768
#define WW 768

// Tiling
#define TW 64            // output tile width
#define TH 32            // output tile height
#define SW 72            // staged (used) width: [tw0-4, tw0+68)
#define SWP 76           // LDS row stride (19 float4-granules; granule 18 = pad)
#define SH (TH + 4)      // 36 staged rows
#define RX 4
#define RY 2
// 256 threads = 16 across x 16 down

// Granule swizzle within a row: kills the tx / tx+8 (delta = 32 floats) bank alias.
// Bijective on 0..18: 0..7 fixed, 8..15 <-> 12..15/8..11, 16..18 fixed.
__device__ __host__ inline int swzg(int g) { return g ^ (((g >> 3) & 1) << 2); }

__global__ __launch_bounds__(256, 4) void colwarp_conv_kernel(
    const float* __restrict__ im,
    const float* __restrict__ flat,
    float* __restrict__ out)
{
    const int tilesW = WW / TW;                 // 12
    const int tile   = blockIdx.x;              // 0..287
    const int b      = blockIdx.y;              // 0..31
    const int tw0    = (tile % tilesW) * TW;
    const int th0    = (tile / tilesW) * TH;

    // 3 * 36 * 76 * 4 = 32832 B -> 4 blocks/CU
    __shared__ float xs[CH][SH][SWP];

    const int tid = threadIdx.x;

    // ---- per-sample params (block-uniform -> scalar) ----
    const float* f = flat + b * 37;
    float Wm[3][3];
#pragma unroll
    for (int d = 0; d < 3; ++d)
#pragma unroll
        for (int c = 0; c < 3; ++c)
            Wm[d][c] = f[d * 3 + c];

    float sh3[3];
#pragma unroll
    for (int d = 0; d < 3; ++d) sh3[d] = f[9 + d];

    float K[5][5];
#pragma unroll
    for (int i = 0; i < 5; ++i)
#pragma unroll
        for (int j = 0; j < 5; ++j)
            K[i][j] = f[12 + i * 5 + j];

    float bias[3];
#pragma unroll
    for (int c = 0; c < 3; ++c)
        bias[c] = sh3[0]*Wm[0][c] + sh3[1]*Wm[1][c] + sh3[2]*Wm[2][c];

    // ---- stage: float4 loads x3 ch, 3x3 mix in regs, SWIZZLED ds_write_b128 ----
    const size_t plane = (size_t)HH * WW;
    const float* im0 = im + (size_t)b * CH * plane;

    for (int u = tid; u < SH * (SW / 4); u += 256) {   // 648 float4 units
        const int r  = u / (SW / 4);
        const int c4 = u - r * (SW / 4);               // 0..17
        const int gh = th0 + r - 2;
        const int gw = tw0 - 4 + c4 * 4;
        const int ldso = r * SWP + swzg(c4) * 4;       // swizzled granule
        float4 m0 = make_float4(0.f, 0.f, 0.f, 0.f);
        float4 m1 = m0, m2 = m0;
        if ((unsigned)gh < (unsigned)HH && (unsigned)gw < (unsigned)WW) {
            const size_t off = (size_t)gh * WW + gw;
            const float4 v0 = *(const float4*)(im0 + off);
            const float4 v1 = *(const float4*)(im0 + plane + off);
            const float4 v2 = *(const float4*)(im0 + 2 * plane + off);
            m0.x = v0.x*Wm[0][0] + v1.x*Wm[1][0] + v2.x*Wm[2][0] + bias[0];
            m0.y = v0.y*Wm[0][0] + v1.y*Wm[1][0] + v2.y*Wm[2][0] + bias[0];
            m0.z = v0.z*Wm[0][0] + v1.z*Wm[1][0] + v2.z*Wm[2][0] + bias[0];
            m0.w = v0.w*Wm[0][0] + v1.w*Wm[1][0] + v2.w*Wm[2][0] + bias[0];
            m1.x = v0.x*Wm[0][1] + v1.x*Wm[1][1] + v2.x*Wm[2][1] + bias[1];
            m1.y = v0.y*Wm[0][1] + v1.y*Wm[1][1] + v2.y*Wm[2][1] + bias[1];
            m1.z = v0.z*Wm[0][1] + v1.z*Wm[1][1] + v2.z*Wm[2][1] + bias[1];
            m1.w = v0.w*Wm[0][1] + v1.w*Wm[1][1] + v2.w*Wm[2][1] + bias[1];
            m2.x = v0.x*Wm[0][2] + v1.x*Wm[1][2] + v2.x*Wm[2][2] + bias[2];
            m2.y = v0.y*Wm[0][2] + v1.y*Wm[1][2] + v2.y*Wm[2][2] + bias[2];
            m2.z = v0.z*Wm[0][2] + v1.z*Wm[1][2] + v2.z*Wm[2][2] + bias[2];
            m2.w = v0.w*Wm[0][2] + v1.w*Wm[1][2] + v2.w*Wm[2][2] + bias[2];
        }
        *(float4*)(&xs[0][0][0] + 0 * (SH * SWP) + ldso) = m0;
        *(float4*)(&xs[0][0][0] + 1 * (SH * SWP) + ldso) = m1;
        *(float4*)(&xs[0][0][0] + 2 * (SH * SWP) + ldso) = m2;
    }
    __syncthreads();

    // ---- conv 5x5 from swizzled LDS, register-blocked 4x2 ----
    const int tx = tid & 15;
    const int ty = tid >> 4;
    const int r0 = ty * RY;

    // This thread's window floats 4tx+2..4tx+9 live in granules tx, tx+1, tx+2.
    // Precompute swizzled float offsets (within a row) once.
    const int offA = swzg(tx) * 4 + 2;       // floats 2,3 of granule tx
    const int offB = swzg(tx + 1) * 4;       // floats 0,1
    const int offC = offB + 2;               // floats 2,3 (same granule)
    const int offD = swzg(tx + 2) * 4;       // floats 0,1

    float acc[CH][RY][RX];
#pragma unroll
    for (int c = 0; c < CH; ++c)
#pragma unroll
        for (int r = 0; r < RY; ++r)
#pragma unroll
            for (int o = 0; o < RX; ++o)
                acc[c][r][o] = 0.f;

#pragma unroll
    for (int rr = 0; rr < RY + 4; ++rr) {
#pragma unroll
        for (int c = 0; c < CH; ++c) {
            const float* rowb = &xs[0][0][0] + c * (SH * SWP) + (r0 + rr) * SWP;
            const float2 p0 = *(const float2*)(rowb + offA);
            const float2 p1 = *(const float2*)(rowb + offB);
            const float2 p2 = *(const float2*)(rowb + offC);
            const float2 p3 = *(const float2*)(rowb + offD);
            const float w8[8] = {p0.x, p0.y, p1.x, p1.y, p2.x, p2.y, p3.x, p3.y};
#pragma unroll
            for (int i = 0; i < 5; ++i) {
                const int r = rr - i;
                if (r >= 0 && r < RY) {
#pragma unroll
                    for (int j = 0; j < 5; ++j) {
#pragma unroll
                        for (int o = 0; o < RX; ++o)
                            acc[c][r][o] += w8[o + j] * K[i][j];
                    }
                }
            }
        }
    }

    // ---- store ----
#pragma unroll
    for (int c = 0; c < CH; ++c) {
        float* ob = out + ((size_t)b * CH + c) * plane;
#pragma unroll
        for (int r = 0; r < RY; ++r) {
            const float4 v = make_float4(acc[c][r][0], acc[c][r][1],
                                         acc[c][r][2], acc[c][r][3]);
            *(float4*)&ob[(size_t)(th0 + r0 + r) * WW + tw0 + tx * RX] = v;
        }
    }
}

extern "C" void kernel_launch(void* const* d_in, const int* in_sizes, int n_in,
                              void* d_out, int out_size, void* d_ws, size_t ws_size,
                              hipStream_t stream) {
    const float* im   = (const float*)d_in[0];
    const float* flat = (const float*)d_in[1];
    float* out        = (float*)d_out;

    dim3 grid((WW / TW) * (HH / TH), NB);  // (288, 32)
    colwarp_conv_kernel<<<grid, 256, 0, stream>>>(im, flat, out);
}